// Round 1
// baseline (2058.974 us; speedup 1.0000x reference)
//
#include <hip/hip_runtime.h>

#define NN 1024
#define WW 64
#define K_CHEB 48

// ---------------- ws layout (float offsets) ----------------
// op      : [0, 1048576)
// rowsum  : [1048576, 1048576+1024)
// scalars : [1049600, 1049608)   {theta, delta, sigma1, lmin}
// r       : [1049856, +65536)
// x       : [1115392, +65536)
// d0      : [1180928, +65536)
// d1      : [1246464, +65536)
// total ≈ 5.25 MB
#define OFF_OP 0
#define OFF_RS 1048576
#define OFF_SC 1049600
#define OFF_R  1049856
#define OFF_X  1115392
#define OFF_D0 1180928
#define OFF_D1 1246464

__global__ __launch_bounds__(256) void zero_rowsum(float* rowsum) {
    int idx = blockIdx.x * 256 + threadIdx.x;
    if (idx < NN) rowsum[idx] = 0.0f;
}

// op = ga*(A A^T)/n + gd*(D D^T)/n + (ga+gd+al)*I ; also Gershgorin row sums
__global__ __launch_bounds__(256)
void form_op(const float* __restrict__ A, const float* __restrict__ Dm,
             const float* __restrict__ ga_p, const float* __restrict__ gd_p,
             const float* __restrict__ al_p,
             float* __restrict__ op, float* __restrict__ rowsum) {
    __shared__ float As[16][68];   // k-major, pad 68: b128-aligned rows (272B), conflict-free
    __shared__ float Bs[16][68];
    __shared__ float Ds[16][68];
    __shared__ float Es[16][68];
    const int t = threadIdx.x;
    const int i0 = blockIdx.y * 64;
    const int j0 = blockIdx.x * 64;
    const int row_l = t >> 2;
    const int kq = (t & 3) * 4;
    const int tx = t & 15, ty = t >> 4;

    float accA[4][4] = {{0.f}}, accD[4][4] = {{0.f}};

    for (int k0 = 0; k0 < NN; k0 += 16) {
        __syncthreads();
        float4 a_i = *(const float4*)(A  + (i0 + row_l) * NN + k0 + kq);
        float4 a_j = *(const float4*)(A  + (j0 + row_l) * NN + k0 + kq);
        float4 d_i = *(const float4*)(Dm + (i0 + row_l) * NN + k0 + kq);
        float4 d_j = *(const float4*)(Dm + (j0 + row_l) * NN + k0 + kq);
        const float* ap = (const float*)&a_i;
        const float* bp = (const float*)&a_j;
        const float* dp = (const float*)&d_i;
        const float* ep = (const float*)&d_j;
        #pragma unroll
        for (int c = 0; c < 4; ++c) {
            As[kq + c][row_l] = ap[c];
            Bs[kq + c][row_l] = bp[c];
            Ds[kq + c][row_l] = dp[c];
            Es[kq + c][row_l] = ep[c];
        }
        __syncthreads();
        #pragma unroll
        for (int k = 0; k < 16; ++k) {
            float4 av = *(const float4*)&As[k][tx * 4];
            float4 bv = *(const float4*)&Bs[k][ty * 4];
            float4 dv = *(const float4*)&Ds[k][tx * 4];
            float4 ev = *(const float4*)&Es[k][ty * 4];
            float am[4] = {av.x, av.y, av.z, av.w};
            float bm[4] = {bv.x, bv.y, bv.z, bv.w};
            float dm[4] = {dv.x, dv.y, dv.z, dv.w};
            float em[4] = {ev.x, ev.y, ev.z, ev.w};
            #pragma unroll
            for (int m = 0; m < 4; ++m)
                #pragma unroll
                for (int n = 0; n < 4; ++n) {
                    accA[m][n] += am[m] * bm[n];
                    accD[m][n] += dm[m] * em[n];
                }
        }
    }

    const float ga = ga_p[0], gd = gd_p[0], al = al_p[0];
    const float inv_n = 1.0f / (float)NN;
    const float diag_add = ga + gd + al;
    float part[4] = {0.f, 0.f, 0.f, 0.f};
    #pragma unroll
    for (int m = 0; m < 4; ++m) {
        const int i = i0 + tx * 4 + m;
        #pragma unroll
        for (int n = 0; n < 4; ++n) {
            const int j = j0 + ty * 4 + n;
            float v = (ga * accA[m][n] + gd * accD[m][n]) * inv_n;
            if (i == j) v += diag_add;
            op[i * NN + j] = v;
            part[m] += fabsf(v);
        }
    }
    // block-level Gershgorin partial reduction: 64 rows x 16 (ty) partials
    __syncthreads();
    float* scratch = &As[0][0];  // 16*68 = 1088 >= 64*17
    #pragma unroll
    for (int m = 0; m < 4; ++m) scratch[(tx * 4 + m) * 17 + ty] = part[m];
    __syncthreads();
    if (t < 64) {
        float s = 0.f;
        #pragma unroll
        for (int q = 0; q < 16; ++q) s += scratch[t * 17 + q];
        atomicAdd(rowsum + i0 + t, s);
    }
}

__global__ __launch_bounds__(256)
void reduce_scalars(const float* __restrict__ rowsum, const float* __restrict__ ga_p,
                    const float* __restrict__ gd_p, const float* __restrict__ al_p,
                    float* __restrict__ scalars) {
    __shared__ float red[256];
    const int t = threadIdx.x;
    float m = 0.f;
    for (int q = t; q < NN; q += 256) m = fmaxf(m, rowsum[q]);
    red[t] = m;
    __syncthreads();
    for (int s = 128; s > 0; s >>= 1) {
        if (t < s) red[t] = fmaxf(red[t], red[t + s]);
        __syncthreads();
    }
    if (t == 0) {
        float lmax = red[0];
        float lmin = ga_p[0] + gd_p[0] + al_p[0];  // rigorous: op >= (ga+gd+al)*I
        if (!(lmin > 0.f)) lmin = 1e-3f;
        if (lmax < lmin * 1.0001f) lmax = lmin * 1.0001f;
        const float theta = 0.5f * (lmax + lmin);
        const float delta = 0.5f * (lmax - lmin);
        scalars[0] = theta;
        scalars[1] = delta;
        scalars[2] = theta / delta;  // sigma1
        scalars[3] = lmin;
    }
}

// x0 = 0 ; r0 = b = fts/dt ; d0 = r0/theta
__global__ __launch_bounds__(256)
void cheb_init(const float* __restrict__ fts, const float* __restrict__ dtime,
               const float* __restrict__ scalars,
               float* __restrict__ r, float* __restrict__ x, float* __restrict__ d0) {
    const int idx = blockIdx.x * 256 + threadIdx.x;
    const int w = idx & 63;
    const float dt = fmaxf(dtime[w], 1e-8f);
    const float b = fts[idx] / dt;
    const float theta = scalars[0];
    r[idx] = b;
    d0[idx] = b / theta;
    x[idx] = 0.f;
}

// One Chebyshev step k (0-based):
//   x += d ; r -= A d ; rho_{k+1} = 1/(2*sigma1 - rho_k) ;
//   d_new = rho_{k+1}*rho_k*d + (2*rho_{k+1}/delta)*r
__global__ __launch_bounds__(256)
void cheb_iter(const float* __restrict__ op, const float* __restrict__ scalars,
               const float* __restrict__ d_in, float* __restrict__ d_out,
               float* __restrict__ r, float* __restrict__ x, int k) {
    __shared__ float dsm[64 * 64];
    __shared__ float op_s[4][64];
    const int t = threadIdx.x;
    const int r_l = t >> 6;       // wave id = local row
    const int w = t & 63;         // lane = RHS column
    const int i = blockIdx.x * 4 + r_l;

    float acc = 0.f;
    for (int jc = 0; jc < 16; ++jc) {
        __syncthreads();
        // stage 64 rows of d (one contiguous 16KB slab), linear copy = coalesced
        const float* src = d_in + jc * 4096;
        #pragma unroll
        for (int u = 0; u < 4; ++u)
            *(float4*)&dsm[u * 1024 + t * 4] = *(const float4*)(src + u * 1024 + t * 4);
        // stage own op row chunk (wave reads 64 consecutive floats)
        op_s[r_l][w] = op[i * NN + jc * 64 + w];
        __syncthreads();
        #pragma unroll
        for (int j = 0; j < 64; j += 4) {
            float4 ov = *(const float4*)&op_s[r_l][j];  // wave-uniform addr -> broadcast
            acc += ov.x * dsm[(j + 0) * 64 + w];
            acc += ov.y * dsm[(j + 1) * 64 + w];
            acc += ov.z * dsm[(j + 2) * 64 + w];
            acc += ov.w * dsm[(j + 3) * 64 + w];
        }
    }

    const float sigma1 = scalars[2];
    const float delta  = scalars[1];
    float rho_k = 1.0f / sigma1;                 // rho_0
    for (int q = 0; q < k; ++q) rho_k = 1.0f / (2.f * sigma1 - rho_k);
    const float rho_n = 1.0f / (2.f * sigma1 - rho_k);

    const int idx = i * WW + w;
    const float d_own = d_in[idx];
    const float x_new = x[idx] + d_own;
    const float r_new = r[idx] - acc;
    const float d_new = rho_n * rho_k * d_own + (2.f * rho_n / delta) * r_new;
    x[idx] = x_new;
    r[idx] = r_new;
    d_out[idx] = d_new;
}

__global__ __launch_bounds__(256)
void finalize(const float* __restrict__ x, float* __restrict__ out) {
    const int idx = blockIdx.x * 256 + threadIdx.x;
    const float v = x[idx];
    out[idx] = v > 0.f ? v : 0.01f * v;
}

extern "C" void kernel_launch(void* const* d_in, const int* in_sizes, int n_in,
                              void* d_out, int out_size, void* d_ws, size_t ws_size,
                              hipStream_t stream) {
    const float* node_fts = (const float*)d_in[0];
    const float* m_adv    = (const float*)d_in[3];
    const float* m_diff   = (const float*)d_in[4];
    const float* dtime    = (const float*)d_in[7];
    const float* ga       = (const float*)d_in[8];
    const float* gd       = (const float*)d_in[9];
    const float* al       = (const float*)d_in[10];
    float* out = (float*)d_out;

    float* ws      = (float*)d_ws;
    float* op      = ws + OFF_OP;
    float* rowsum  = ws + OFF_RS;
    float* scalars = ws + OFF_SC;
    float* rbuf    = ws + OFF_R;
    float* xbuf    = ws + OFF_X;
    float* dbuf0   = ws + OFF_D0;
    float* dbuf1   = ws + OFF_D1;

    zero_rowsum<<<4, 256, 0, stream>>>(rowsum);
    form_op<<<dim3(16, 16), 256, 0, stream>>>(m_adv, m_diff, ga, gd, al, op, rowsum);
    reduce_scalars<<<1, 256, 0, stream>>>(rowsum, ga, gd, al, scalars);
    cheb_init<<<256, 256, 0, stream>>>(node_fts, dtime, scalars, rbuf, xbuf, dbuf0);
    for (int k = 0; k < K_CHEB; ++k) {
        const float* din = (k & 1) ? dbuf1 : dbuf0;
        float*       dut = (k & 1) ? dbuf0 : dbuf1;
        cheb_iter<<<256, 256, 0, stream>>>(op, scalars, din, dut, rbuf, xbuf, k);
    }
    finalize<<<256, 256, 0, stream>>>(xbuf, out);
}

// Round 6
// 1494.386 us; speedup vs baseline: 1.3778x; 1.3778x over previous
//
#include <hip/hip_runtime.h>
#include <hip/hip_cooperative_groups.h>

namespace cg = cooperative_groups;

#define NN 1024
#define WW 64
#define K_CHEB 32

// ---------------- ws layout (float offsets) ----------------
#define OFF_OP 0          // 1024*1024 floats
#define OFF_RS 1048576    // 1024
#define OFF_SC 1049600    // 8
#define OFF_D0 1049856    // 65536
#define OFF_D1 1115392    // 65536

__global__ __launch_bounds__(256) void zero_rowsum(float* rowsum) {
    int idx = blockIdx.x * 256 + threadIdx.x;
    if (idx < NN) rowsum[idx] = 0.0f;
}

// op = ga*(A A^T)/n + gd*(D D^T)/n + (ga+gd+al)*I ; also Gershgorin row sums
__global__ __launch_bounds__(256)
void form_op(const float* __restrict__ A, const float* __restrict__ Dm,
             const float* __restrict__ ga_p, const float* __restrict__ gd_p,
             const float* __restrict__ al_p,
             float* __restrict__ op, float* __restrict__ rowsum) {
    __shared__ float As[16][68];
    __shared__ float Bs[16][68];
    __shared__ float Ds[16][68];
    __shared__ float Es[16][68];
    const int t = threadIdx.x;
    const int i0 = blockIdx.y * 64;
    const int j0 = blockIdx.x * 64;
    const int row_l = t >> 2;
    const int kq = (t & 3) * 4;
    const int tx = t & 15, ty = t >> 4;

    float accA[4][4] = {{0.f}}, accD[4][4] = {{0.f}};

    for (int k0 = 0; k0 < NN; k0 += 16) {
        __syncthreads();
        float4 a_i = *(const float4*)(A  + (i0 + row_l) * NN + k0 + kq);
        float4 a_j = *(const float4*)(A  + (j0 + row_l) * NN + k0 + kq);
        float4 d_i = *(const float4*)(Dm + (i0 + row_l) * NN + k0 + kq);
        float4 d_j = *(const float4*)(Dm + (j0 + row_l) * NN + k0 + kq);
        const float* ap = (const float*)&a_i;
        const float* bp = (const float*)&a_j;
        const float* dp = (const float*)&d_i;
        const float* ep = (const float*)&d_j;
        #pragma unroll
        for (int c = 0; c < 4; ++c) {
            As[kq + c][row_l] = ap[c];
            Bs[kq + c][row_l] = bp[c];
            Ds[kq + c][row_l] = dp[c];
            Es[kq + c][row_l] = ep[c];
        }
        __syncthreads();
        #pragma unroll
        for (int k = 0; k < 16; ++k) {
            float4 av = *(const float4*)&As[k][tx * 4];
            float4 bv = *(const float4*)&Bs[k][ty * 4];
            float4 dv = *(const float4*)&Ds[k][tx * 4];
            float4 ev = *(const float4*)&Es[k][ty * 4];
            float am[4] = {av.x, av.y, av.z, av.w};
            float bm[4] = {bv.x, bv.y, bv.z, bv.w};
            float dm[4] = {dv.x, dv.y, dv.z, dv.w};
            float em[4] = {ev.x, ev.y, ev.z, ev.w};
            #pragma unroll
            for (int m = 0; m < 4; ++m)
                #pragma unroll
                for (int n = 0; n < 4; ++n) {
                    accA[m][n] += am[m] * bm[n];
                    accD[m][n] += dm[m] * em[n];
                }
        }
    }

    const float ga = ga_p[0], gd = gd_p[0], al = al_p[0];
    const float inv_n = 1.0f / (float)NN;
    const float diag_add = ga + gd + al;
    float part[4] = {0.f, 0.f, 0.f, 0.f};
    #pragma unroll
    for (int m = 0; m < 4; ++m) {
        const int i = i0 + tx * 4 + m;
        #pragma unroll
        for (int n = 0; n < 4; ++n) {
            const int j = j0 + ty * 4 + n;
            float v = (ga * accA[m][n] + gd * accD[m][n]) * inv_n;
            if (i == j) v += diag_add;
            op[i * NN + j] = v;
            part[m] += fabsf(v);
        }
    }
    __syncthreads();
    float* scratch = &As[0][0];
    #pragma unroll
    for (int m = 0; m < 4; ++m) scratch[(tx * 4 + m) * 17 + ty] = part[m];
    __syncthreads();
    if (t < 64) {
        float s = 0.f;
        #pragma unroll
        for (int q = 0; q < 16; ++q) s += scratch[t * 17 + q];
        atomicAdd(rowsum + i0 + t, s);
    }
}

__global__ __launch_bounds__(256)
void reduce_scalars(const float* __restrict__ rowsum, const float* __restrict__ ga_p,
                    const float* __restrict__ gd_p, const float* __restrict__ al_p,
                    float* __restrict__ scalars) {
    __shared__ float red[256];
    const int t = threadIdx.x;
    float m = 0.f;
    for (int q = t; q < NN; q += 256) m = fmaxf(m, rowsum[q]);
    red[t] = m;
    __syncthreads();
    for (int s = 128; s > 0; s >>= 1) {
        if (t < s) red[t] = fmaxf(red[t], red[t + s]);
        __syncthreads();
    }
    if (t == 0) {
        float lmax = red[0];
        float lmin = ga_p[0] + gd_p[0] + al_p[0];
        if (!(lmin > 0.f)) lmin = 1e-3f;
        if (lmax < lmin * 1.0001f) lmax = lmin * 1.0001f;
        const float theta = 0.5f * (lmax + lmin);
        const float delta = 0.5f * (lmax - lmin);
        scalars[0] = theta;
        scalars[1] = delta;
        scalars[2] = theta / delta;  // sigma1
        scalars[3] = lmin;
    }
}

// async global(16B) -> LDS, linear layout both sides
#define GLOAD16(g, l)                                                        \
    __builtin_amdgcn_global_load_lds(                                        \
        (const __attribute__((address_space(1))) void*)(g),                  \
        (__attribute__((address_space(3))) void*)(l), 16, 0, 0)

__device__ __forceinline__ void stage16k(const float* __restrict__ g, float* l, int t) {
    #pragma unroll
    for (int u = 0; u < 4; ++u) {
        const int o = (u * 256 + t) * 4;
        GLOAD16(g + o, l + o);
    }
}

// Fused: init + K_CHEB Chebyshev iterations + final x+=d + leaky-relu.
// Block b owns rows [4b, 4b+4). x,r,d for its 4x64 slice live in registers.
// op rows staged to LDS once. d chunks double-buffered with counted vmcnt.
__global__ __launch_bounds__(256)
void cheb_fused(const float* __restrict__ op, const float* __restrict__ scalars,
                const float* __restrict__ fts, const float* __restrict__ dtime,
                float* __restrict__ d0, float* __restrict__ d1,
                float* __restrict__ out) {
    cg::grid_group grid = cg::this_grid();
    __shared__ float op_s[4 * NN];        // 16 KB, persistent all iterations
    __shared__ float dbuf[2][4096];       // 2 x 16 KB chunk double-buffer
    __shared__ float red_s[4][16][16];    // 4 KB cross-wave reduction

    const int t = threadIdx.x;
    const int b = blockIdx.x;
    const int i0 = b * 4;

    // update-phase mapping: element (row i0+rr_u, col w_u)
    const int rr_u = t >> 6;
    const int w_u  = t & 63;
    // matvec mapping: 4 cols starting c0, j-group jg (4 j per chunk)
    const int c0 = (t & 15) * 4;
    const int jg = t >> 4;

    // stage op rows (16 KB contiguous) once
    stage16k(op + i0 * NN, op_s, t);

    const float theta  = scalars[0];
    const float delta  = scalars[1];
    const float sigma1 = scalars[2];

    // init own elements
    const float dtw  = fmaxf(dtime[w_u], 1e-8f);
    const float bval = fts[i0 * WW + t] / dtw;
    float x_e = 0.f, r_e = bval, d_e = bval / theta;
    d0[i0 * WW + t] = d_e;

    asm volatile("s_waitcnt vmcnt(0)" ::: "memory");
    __builtin_amdgcn_sched_barrier(0);
    __syncthreads();     // op_s ready for all waves
    grid.sync();         // d0 globally visible

    float rho = 1.0f / sigma1;

    for (int k = 0; k < K_CHEB; ++k) {
        const float* din = (k & 1) ? d1 : d0;
        float*      dout = (k & 1) ? d0 : d1;

        float4 a0 = {0.f,0.f,0.f,0.f}, a1 = a0, a2 = a0, a3 = a0;

        stage16k(din, dbuf[0], t);                       // chunk 0
        for (int c = 0; c < 16; ++c) {
            const int cur = c & 1;
            if (c < 15) {
                stage16k(din + (c + 1) * 4096, dbuf[cur ^ 1], t);
                asm volatile("s_waitcnt vmcnt(4)" ::: "memory");
            } else {
                asm volatile("s_waitcnt vmcnt(0)" ::: "memory");
            }
            __builtin_amdgcn_sched_barrier(0);
            __builtin_amdgcn_s_barrier();                // chunk c ready

            const float* db = dbuf[cur];
            const int jb = jg * 4;
            float4 o0 = *(const float4*)&op_s[0 * NN + c * 64 + jb];
            float4 o1 = *(const float4*)&op_s[1 * NN + c * 64 + jb];
            float4 o2 = *(const float4*)&op_s[2 * NN + c * 64 + jb];
            float4 o3 = *(const float4*)&op_s[3 * NN + c * 64 + jb];
            #pragma unroll
            for (int jj = 0; jj < 4; ++jj) {
                float4 dv = *(const float4*)&db[(jb + jj) * 64 + c0];
                const float f0 = ((const float*)&o0)[jj];
                const float f1 = ((const float*)&o1)[jj];
                const float f2 = ((const float*)&o2)[jj];
                const float f3 = ((const float*)&o3)[jj];
                a0.x += f0 * dv.x; a0.y += f0 * dv.y; a0.z += f0 * dv.z; a0.w += f0 * dv.w;
                a1.x += f1 * dv.x; a1.y += f1 * dv.y; a1.z += f1 * dv.z; a1.w += f1 * dv.w;
                a2.x += f2 * dv.x; a2.y += f2 * dv.y; a2.z += f2 * dv.z; a2.w += f2 * dv.w;
                a3.x += f3 * dv.x; a3.y += f3 * dv.y; a3.z += f3 * dv.z; a3.w += f3 * dv.w;
            }
            asm volatile("s_waitcnt lgkmcnt(0)" ::: "memory");
            __builtin_amdgcn_sched_barrier(0);
            __builtin_amdgcn_s_barrier();                // all done reading dbuf[cur]
        }

        // reduce over the 16 jg groups. a[v], v = r*4 + cc
        float a[16] = {a0.x, a0.y, a0.z, a0.w, a1.x, a1.y, a1.z, a1.w,
                       a2.x, a2.y, a2.z, a2.w, a3.x, a3.y, a3.z, a3.w};
        #pragma unroll
        for (int v = 0; v < 16; ++v) {
            a[v] += __shfl_xor(a[v], 16, 64);
            a[v] += __shfl_xor(a[v], 32, 64);
        }
        const int wv = t >> 6, lane = t & 63;
        if (lane < 16) {
            #pragma unroll
            for (int v = 0; v < 16; ++v) red_s[wv][lane][v] = a[v];
        }
        __syncthreads();
        const int ri = w_u >> 2;
        const int vi = rr_u * 4 + (w_u & 3);
        const float q = red_s[0][ri][vi] + red_s[1][ri][vi] +
                        red_s[2][ri][vi] + red_s[3][ri][vi];

        // Chebyshev update (row-local, registers)
        x_e += d_e;
        r_e -= q;
        const float rho_n = 1.0f / (2.f * sigma1 - rho);
        d_e = rho_n * rho * d_e + (2.f * rho_n / delta) * r_e;
        rho = rho_n;
        dout[i0 * WW + t] = d_e;

        grid.sync();   // dout visible to all before next matvec
    }

    // closing half-step + leaky relu
    x_e += d_e;
    out[i0 * WW + t] = x_e > 0.f ? x_e : 0.01f * x_e;
}

extern "C" void kernel_launch(void* const* d_in, const int* in_sizes, int n_in,
                              void* d_out, int out_size, void* d_ws, size_t ws_size,
                              hipStream_t stream) {
    const float* node_fts = (const float*)d_in[0];
    const float* m_adv    = (const float*)d_in[3];
    const float* m_diff   = (const float*)d_in[4];
    const float* dtime    = (const float*)d_in[7];
    const float* ga       = (const float*)d_in[8];
    const float* gd       = (const float*)d_in[9];
    const float* al       = (const float*)d_in[10];
    float* out = (float*)d_out;

    float* ws      = (float*)d_ws;
    float* op      = ws + OFF_OP;
    float* rowsum  = ws + OFF_RS;
    float* scalars = ws + OFF_SC;
    float* dbuf0   = ws + OFF_D0;
    float* dbuf1   = ws + OFF_D1;

    zero_rowsum<<<4, 256, 0, stream>>>(rowsum);
    form_op<<<dim3(16, 16), 256, 0, stream>>>(m_adv, m_diff, ga, gd, al, op, rowsum);
    reduce_scalars<<<1, 256, 0, stream>>>(rowsum, ga, gd, al, scalars);

    const float* c_op = op; const float* c_sc = scalars;
    void* args[] = {(void*)&c_op, (void*)&c_sc, (void*)&node_fts, (void*)&dtime,
                    (void*)&dbuf0, (void*)&dbuf1, (void*)&out};
    hipLaunchCooperativeKernel(reinterpret_cast<void*>(cheb_fused),
                               dim3(256), dim3(256), args, 0, stream);
}

// Round 10
// 883.974 us; speedup vs baseline: 2.3292x; 1.6905x over previous
//
#include <hip/hip_runtime.h>

#define NN 1024
#define WW 64
#define K_CHEB 48
#define NBLK 256

// ---------------- ws layout (float offsets) ----------------
#define OFF_OP  0          // 1024*1024 floats
#define OFF_RS  1048576    // 1024 floats
#define OFF_SC  1049600    // 8 floats {theta, delta, sigma1, lmin}
#define OFF_CNT 1049728    // 49*544 = 26656 ints (barrier counters, padded leaves)
#define OFF_FLG 1076480    // 64 ints (barrier flags)
#define OFF_D0  1076608    // 65536 floats
#define OFF_D1  1142144    // 65536 floats
// total ~4.83 MB

__global__ __launch_bounds__(256)
void zero_aux(float* rowsum, int* cnt, int* flg) {
    int idx = blockIdx.x * 256 + threadIdx.x;
    if (idx < NN) rowsum[idx] = 0.0f;
    if (idx < 64) flg[idx] = 0;
    if (idx < 49 * 544) cnt[idx] = 0;
}

// op = ga*(A A^T)/n + gd*(D D^T)/n + (ga+gd+al)*I ; also Gershgorin row sums
__global__ __launch_bounds__(256)
void form_op(const float* __restrict__ A, const float* __restrict__ Dm,
             const float* __restrict__ ga_p, const float* __restrict__ gd_p,
             const float* __restrict__ al_p,
             float* __restrict__ op, float* __restrict__ rowsum) {
    __shared__ float As[16][68];
    __shared__ float Bs[16][68];
    __shared__ float Ds[16][68];
    __shared__ float Es[16][68];
    const int t = threadIdx.x;
    const int i0 = blockIdx.y * 64;
    const int j0 = blockIdx.x * 64;
    const int row_l = t >> 2;
    const int kq = (t & 3) * 4;
    const int tx = t & 15, ty = t >> 4;

    float accA[4][4] = {{0.f}}, accD[4][4] = {{0.f}};

    for (int k0 = 0; k0 < NN; k0 += 16) {
        __syncthreads();
        float4 a_i = *(const float4*)(A  + (i0 + row_l) * NN + k0 + kq);
        float4 a_j = *(const float4*)(A  + (j0 + row_l) * NN + k0 + kq);
        float4 d_i = *(const float4*)(Dm + (i0 + row_l) * NN + k0 + kq);
        float4 d_j = *(const float4*)(Dm + (j0 + row_l) * NN + k0 + kq);
        const float* ap = (const float*)&a_i;
        const float* bp = (const float*)&a_j;
        const float* dp = (const float*)&d_i;
        const float* ep = (const float*)&d_j;
        #pragma unroll
        for (int c = 0; c < 4; ++c) {
            As[kq + c][row_l] = ap[c];
            Bs[kq + c][row_l] = bp[c];
            Ds[kq + c][row_l] = dp[c];
            Es[kq + c][row_l] = ep[c];
        }
        __syncthreads();
        #pragma unroll
        for (int k = 0; k < 16; ++k) {
            float4 av = *(const float4*)&As[k][tx * 4];
            float4 bv = *(const float4*)&Bs[k][ty * 4];
            float4 dv = *(const float4*)&Ds[k][tx * 4];
            float4 ev = *(const float4*)&Es[k][ty * 4];
            float am[4] = {av.x, av.y, av.z, av.w};
            float bm[4] = {bv.x, bv.y, bv.z, bv.w};
            float dm[4] = {dv.x, dv.y, dv.z, dv.w};
            float em[4] = {ev.x, ev.y, ev.z, ev.w};
            #pragma unroll
            for (int m = 0; m < 4; ++m)
                #pragma unroll
                for (int n = 0; n < 4; ++n) {
                    accA[m][n] += am[m] * bm[n];
                    accD[m][n] += dm[m] * em[n];
                }
        }
    }

    const float ga = ga_p[0], gd = gd_p[0], al = al_p[0];
    const float inv_n = 1.0f / (float)NN;
    const float diag_add = ga + gd + al;
    float part[4] = {0.f, 0.f, 0.f, 0.f};
    #pragma unroll
    for (int m = 0; m < 4; ++m) {
        const int i = i0 + tx * 4 + m;
        #pragma unroll
        for (int n = 0; n < 4; ++n) {
            const int j = j0 + ty * 4 + n;
            float v = (ga * accA[m][n] + gd * accD[m][n]) * inv_n;
            if (i == j) v += diag_add;
            op[i * NN + j] = v;
            part[m] += fabsf(v);
        }
    }
    __syncthreads();
    float* scratch = &As[0][0];
    #pragma unroll
    for (int m = 0; m < 4; ++m) scratch[(tx * 4 + m) * 17 + ty] = part[m];
    __syncthreads();
    if (t < 64) {
        float s = 0.f;
        #pragma unroll
        for (int q = 0; q < 16; ++q) s += scratch[t * 17 + q];
        atomicAdd(rowsum + i0 + t, s);
    }
}

__global__ __launch_bounds__(256)
void reduce_scalars(const float* __restrict__ rowsum, const float* __restrict__ ga_p,
                    const float* __restrict__ gd_p, const float* __restrict__ al_p,
                    float* __restrict__ scalars) {
    __shared__ float red[256];
    const int t = threadIdx.x;
    float m = 0.f;
    for (int q = t; q < NN; q += 256) m = fmaxf(m, rowsum[q]);
    red[t] = m;
    __syncthreads();
    for (int s = 128; s > 0; s >>= 1) {
        if (t < s) red[t] = fmaxf(red[t], red[t + s]);
        __syncthreads();
    }
    if (t == 0) {
        float lmax = red[0];
        float lmin = ga_p[0] + gd_p[0] + al_p[0];
        if (!(lmin > 0.f)) lmin = 1e-3f;
        if (lmax < lmin * 1.0001f) lmax = lmin * 1.0001f;
        const float theta = 0.5f * (lmax + lmin);
        const float delta = 0.5f * (lmax - lmin);
        scalars[0] = theta;
        scalars[1] = delta;
        scalars[2] = theta / delta;  // sigma1
        scalars[3] = lmin;
    }
}

// async global(16B) -> LDS, linear layout both sides
#define GLOAD16(g, l)                                                        \
    __builtin_amdgcn_global_load_lds(                                        \
        (const __attribute__((address_space(1))) void*)(g),                  \
        (__attribute__((address_space(3))) void*)(l), 16, 0, 0)

__device__ __forceinline__ void stage16k(const float* __restrict__ g, float* l, int t) {
    #pragma unroll
    for (int u = 0; u < 4; ++u) {
        const int o = (u * 256 + t) * 4;
        GLOAD16(g + o, l + o);
    }
}

// Lightweight device-wide barrier, slot k.
// Prereq: this block's shared-data stores were system-scope atomic stores.
// vmcnt(0)+syncthreads drains them; 2-level counter tree (16 padded leaves +
// root) -> flag; spin via system-scope loads; buffer_inv sc1 = acquire
// (invalidate stale L2 lines) -- no wbl2 needed, no full cg fence.
__device__ __forceinline__ void gbarrier(int* cnt, int* flg, int k, int bid) {
    asm volatile("s_waitcnt vmcnt(0)" ::: "memory");
    __syncthreads();
    if (threadIdx.x == 0) {
        int* c = cnt + k * 544;
        bool last = false;
        if (atomicAdd(&c[(bid & 15) * 32], 1) == 15) {
            if (atomicAdd(&c[512], 1) == 15) {
                __hip_atomic_store(&flg[k], 1, __ATOMIC_RELAXED, __HIP_MEMORY_SCOPE_SYSTEM);
                last = true;
            }
        }
        if (!last) {
            while (__hip_atomic_load(&flg[k], __ATOMIC_RELAXED, __HIP_MEMORY_SCOPE_SYSTEM) == 0) {
                __builtin_amdgcn_s_sleep(1);
            }
        }
        asm volatile("buffer_inv sc1" ::: "memory");
        asm volatile("s_waitcnt vmcnt(0)" ::: "memory");
    }
    __syncthreads();
}

// Fused: init + K_CHEB Chebyshev iterations + final x+=d + leaky-relu.
// Block b owns rows [4b, 4b+4). x,r,d slice in registers; op rows in LDS.
__global__ __launch_bounds__(256)
void cheb_fused(const float* __restrict__ op, const float* __restrict__ scalars,
                const float* __restrict__ fts, const float* __restrict__ dtime,
                float* __restrict__ d0, float* __restrict__ d1,
                int* __restrict__ cnt, int* __restrict__ flg,
                float* __restrict__ out) {
    __shared__ float op_s[4 * NN];        // 16 KB, persistent all iterations
    __shared__ float dbuf[2][4096];       // 2 x 16 KB chunk double-buffer
    __shared__ float red_s[4][16][16];    // 4 KB cross-wave reduction

    const int t = threadIdx.x;
    const int b = blockIdx.x;
    const int i0 = b * 4;

    const int rr_u = t >> 6;
    const int w_u  = t & 63;
    const int c0 = (t & 15) * 4;
    const int jg = t >> 4;

    // stage op rows (16 KB contiguous) once
    stage16k(op + i0 * NN, op_s, t);

    const float theta  = scalars[0];
    const float delta  = scalars[1];
    const float sigma1 = scalars[2];

    // init own elements; d0 published system-scope (visible at L3)
    const float dtw  = fmaxf(dtime[w_u], 1e-8f);
    const float bval = fts[i0 * WW + t] / dtw;
    float x_e = 0.f, r_e = bval, d_e = bval / theta;
    __hip_atomic_store(&d0[i0 * WW + t], d_e, __ATOMIC_RELAXED, __HIP_MEMORY_SCOPE_SYSTEM);

    asm volatile("s_waitcnt vmcnt(0)" ::: "memory");
    __builtin_amdgcn_sched_barrier(0);
    __syncthreads();     // op_s ready for all waves
    gbarrier(cnt, flg, 0, b);   // d0 globally visible

    float rho = 1.0f / sigma1;

    for (int k = 0; k < K_CHEB; ++k) {
        const float* din = (k & 1) ? d1 : d0;
        float*      dout = (k & 1) ? d0 : d1;

        float4 a0 = {0.f,0.f,0.f,0.f}, a1 = a0, a2 = a0, a3 = a0;

        stage16k(din, dbuf[0], t);                       // chunk 0
        for (int c = 0; c < 16; ++c) {
            const int cur = c & 1;
            if (c < 15) {
                stage16k(din + (c + 1) * 4096, dbuf[cur ^ 1], t);
                asm volatile("s_waitcnt vmcnt(4)" ::: "memory");
            } else {
                asm volatile("s_waitcnt vmcnt(0)" ::: "memory");
            }
            __builtin_amdgcn_sched_barrier(0);
            __builtin_amdgcn_s_barrier();                // chunk c ready

            const float* db = dbuf[cur];
            const int jb = jg * 4;
            float4 o0 = *(const float4*)&op_s[0 * NN + c * 64 + jb];
            float4 o1 = *(const float4*)&op_s[1 * NN + c * 64 + jb];
            float4 o2 = *(const float4*)&op_s[2 * NN + c * 64 + jb];
            float4 o3 = *(const float4*)&op_s[3 * NN + c * 64 + jb];
            #pragma unroll
            for (int jj = 0; jj < 4; ++jj) {
                float4 dv = *(const float4*)&db[(jb + jj) * 64 + c0];
                const float f0 = ((const float*)&o0)[jj];
                const float f1 = ((const float*)&o1)[jj];
                const float f2 = ((const float*)&o2)[jj];
                const float f3 = ((const float*)&o3)[jj];
                a0.x += f0 * dv.x; a0.y += f0 * dv.y; a0.z += f0 * dv.z; a0.w += f0 * dv.w;
                a1.x += f1 * dv.x; a1.y += f1 * dv.y; a1.z += f1 * dv.z; a1.w += f1 * dv.w;
                a2.x += f2 * dv.x; a2.y += f2 * dv.y; a2.z += f2 * dv.z; a2.w += f2 * dv.w;
                a3.x += f3 * dv.x; a3.y += f3 * dv.y; a3.z += f3 * dv.z; a3.w += f3 * dv.w;
            }
            asm volatile("s_waitcnt lgkmcnt(0)" ::: "memory");
            __builtin_amdgcn_sched_barrier(0);
            __builtin_amdgcn_s_barrier();                // all done reading dbuf[cur]
        }

        // reduce over the 16 jg groups. a[v], v = row*4 + col-sub
        float a[16] = {a0.x, a0.y, a0.z, a0.w, a1.x, a1.y, a1.z, a1.w,
                       a2.x, a2.y, a2.z, a2.w, a3.x, a3.y, a3.z, a3.w};
        #pragma unroll
        for (int v = 0; v < 16; ++v) {
            a[v] += __shfl_xor(a[v], 16, 64);
            a[v] += __shfl_xor(a[v], 32, 64);
        }
        const int wv = t >> 6, lane = t & 63;
        if (lane < 16) {
            #pragma unroll
            for (int v = 0; v < 16; ++v) red_s[wv][lane][v] = a[v];
        }
        __syncthreads();
        const int ri = w_u >> 2;
        const int vi = rr_u * 4 + (w_u & 3);
        const float q = red_s[0][ri][vi] + red_s[1][ri][vi] +
                        red_s[2][ri][vi] + red_s[3][ri][vi];

        // Chebyshev update (row-local, registers)
        x_e += d_e;
        r_e -= q;
        const float rho_n = 1.0f / (2.f * sigma1 - rho);
        d_e = rho_n * rho * d_e + (2.f * rho_n / delta) * r_e;
        rho = rho_n;
        __hip_atomic_store(&dout[i0 * WW + t], d_e, __ATOMIC_RELAXED, __HIP_MEMORY_SCOPE_SYSTEM);

        gbarrier(cnt, flg, k + 1, b);   // dout visible to all before next matvec
    }

    // closing half-step + leaky relu
    x_e += d_e;
    out[i0 * WW + t] = x_e > 0.f ? x_e : 0.01f * x_e;
}

extern "C" void kernel_launch(void* const* d_in, const int* in_sizes, int n_in,
                              void* d_out, int out_size, void* d_ws, size_t ws_size,
                              hipStream_t stream) {
    const float* node_fts = (const float*)d_in[0];
    const float* m_adv    = (const float*)d_in[3];
    const float* m_diff   = (const float*)d_in[4];
    const float* dtime    = (const float*)d_in[7];
    const float* ga       = (const float*)d_in[8];
    const float* gd       = (const float*)d_in[9];
    const float* al       = (const float*)d_in[10];
    float* out = (float*)d_out;

    float* ws      = (float*)d_ws;
    float* op      = ws + OFF_OP;
    float* rowsum  = ws + OFF_RS;
    float* scalars = ws + OFF_SC;
    int*   cnt     = (int*)(ws + OFF_CNT);
    int*   flg     = (int*)(ws + OFF_FLG);
    float* dbuf0   = ws + OFF_D0;
    float* dbuf1   = ws + OFF_D1;

    zero_aux<<<105, 256, 0, stream>>>(rowsum, cnt, flg);
    form_op<<<dim3(16, 16), 256, 0, stream>>>(m_adv, m_diff, ga, gd, al, op, rowsum);
    reduce_scalars<<<1, 256, 0, stream>>>(rowsum, ga, gd, al, scalars);

    const float* c_op = op; const float* c_sc = scalars;
    void* args[] = {(void*)&c_op, (void*)&c_sc, (void*)&node_fts, (void*)&dtime,
                    (void*)&dbuf0, (void*)&dbuf1, (void*)&cnt, (void*)&flg,
                    (void*)&out};
    hipLaunchCooperativeKernel(reinterpret_cast<void*>(cheb_fused),
                               dim3(NBLK), dim3(256), args, 0, stream);
}

// Round 11
// 593.382 us; speedup vs baseline: 3.4699x; 1.4897x over previous
//
#include <hip/hip_runtime.h>

#define NN 1024
#define WW 64
#define K_CHEB 32
#define NBLK 256

// ---------------- ws layout (float offsets) ----------------
#define OFF_OP  0          // 1024*1024 floats
#define OFF_RS  1048576    // 1024 floats
#define OFF_SC  1049600    // 8 floats {theta, delta, sigma1, lmin}
#define OFF_CNT 1049728    // 49*544 ints (barrier counters, padded leaves)
#define OFF_FLG 1076480    // 64 ints (barrier flags)
#define OFF_D0  1076608    // 65536 floats
#define OFF_D1  1142144    // 65536 floats

__global__ __launch_bounds__(256)
void zero_aux(float* rowsum, int* cnt, int* flg) {
    int idx = blockIdx.x * 256 + threadIdx.x;
    if (idx < NN) rowsum[idx] = 0.0f;
    if (idx < 64) flg[idx] = 0;
    if (idx < 49 * 544) cnt[idx] = 0;
}

// op = ga*(A A^T)/n + gd*(D D^T)/n + (ga+gd+al)*I ; also Gershgorin row sums
// k-tile staging is register-prefetched: loads for k0+16 issue during k0 compute.
__global__ __launch_bounds__(256)
void form_op(const float* __restrict__ A, const float* __restrict__ Dm,
             const float* __restrict__ ga_p, const float* __restrict__ gd_p,
             const float* __restrict__ al_p,
             float* __restrict__ op, float* __restrict__ rowsum) {
    __shared__ float As[16][68];
    __shared__ float Bs[16][68];
    __shared__ float Ds[16][68];
    __shared__ float Es[16][68];
    const int t = threadIdx.x;
    const int i0 = blockIdx.y * 64;
    const int j0 = blockIdx.x * 64;
    const int row_l = t >> 2;
    const int kq = (t & 3) * 4;
    const int tx = t & 15, ty = t >> 4;

    const float* pAi = A  + (i0 + row_l) * NN + kq;
    const float* pAj = A  + (j0 + row_l) * NN + kq;
    const float* pDi = Dm + (i0 + row_l) * NN + kq;
    const float* pDj = Dm + (j0 + row_l) * NN + kq;

    float accA[4][4] = {{0.f}}, accD[4][4] = {{0.f}};

    float4 ra = *(const float4*)(pAi);
    float4 rb = *(const float4*)(pAj);
    float4 rd = *(const float4*)(pDi);
    float4 re = *(const float4*)(pDj);

    for (int k0 = 0; k0 < NN; k0 += 16) {
        __syncthreads();   // LDS free (previous compute done)
        {
            const float* ap = (const float*)&ra;
            const float* bp = (const float*)&rb;
            const float* dp = (const float*)&rd;
            const float* ep = (const float*)&re;
            #pragma unroll
            for (int c = 0; c < 4; ++c) {
                As[kq + c][row_l] = ap[c];
                Bs[kq + c][row_l] = bp[c];
                Ds[kq + c][row_l] = dp[c];
                Es[kq + c][row_l] = ep[c];
            }
        }
        if (k0 + 16 < NN) {   // prefetch next k-tile; completes under compute
            ra = *(const float4*)(pAi + k0 + 16);
            rb = *(const float4*)(pAj + k0 + 16);
            rd = *(const float4*)(pDi + k0 + 16);
            re = *(const float4*)(pDj + k0 + 16);
        }
        __syncthreads();   // LDS ready
        #pragma unroll
        for (int k = 0; k < 16; ++k) {
            float4 av = *(const float4*)&As[k][tx * 4];
            float4 bv = *(const float4*)&Bs[k][ty * 4];
            float4 dv = *(const float4*)&Ds[k][tx * 4];
            float4 ev = *(const float4*)&Es[k][ty * 4];
            float am[4] = {av.x, av.y, av.z, av.w};
            float bm[4] = {bv.x, bv.y, bv.z, bv.w};
            float dm[4] = {dv.x, dv.y, dv.z, dv.w};
            float em[4] = {ev.x, ev.y, ev.z, ev.w};
            #pragma unroll
            for (int m = 0; m < 4; ++m)
                #pragma unroll
                for (int n = 0; n < 4; ++n) {
                    accA[m][n] += am[m] * bm[n];
                    accD[m][n] += dm[m] * em[n];
                }
        }
    }

    const float ga = ga_p[0], gd = gd_p[0], al = al_p[0];
    const float inv_n = 1.0f / (float)NN;
    const float diag_add = ga + gd + al;
    float part[4] = {0.f, 0.f, 0.f, 0.f};
    #pragma unroll
    for (int m = 0; m < 4; ++m) {
        const int i = i0 + tx * 4 + m;
        #pragma unroll
        for (int n = 0; n < 4; ++n) {
            const int j = j0 + ty * 4 + n;
            float v = (ga * accA[m][n] + gd * accD[m][n]) * inv_n;
            if (i == j) v += diag_add;
            op[i * NN + j] = v;
            part[m] += fabsf(v);
        }
    }
    __syncthreads();
    float* scratch = &As[0][0];
    #pragma unroll
    for (int m = 0; m < 4; ++m) scratch[(tx * 4 + m) * 17 + ty] = part[m];
    __syncthreads();
    if (t < 64) {
        float s = 0.f;
        #pragma unroll
        for (int q = 0; q < 16; ++q) s += scratch[t * 17 + q];
        atomicAdd(rowsum + i0 + t, s);
    }
}

__global__ __launch_bounds__(256)
void reduce_scalars(const float* __restrict__ rowsum, const float* __restrict__ ga_p,
                    const float* __restrict__ gd_p, const float* __restrict__ al_p,
                    float* __restrict__ scalars) {
    __shared__ float red[256];
    const int t = threadIdx.x;
    float m = 0.f;
    for (int q = t; q < NN; q += 256) m = fmaxf(m, rowsum[q]);
    red[t] = m;
    __syncthreads();
    for (int s = 128; s > 0; s >>= 1) {
        if (t < s) red[t] = fmaxf(red[t], red[t + s]);
        __syncthreads();
    }
    if (t == 0) {
        float lmax = red[0];
        float lmin = ga_p[0] + gd_p[0] + al_p[0];
        if (!(lmin > 0.f)) lmin = 1e-3f;
        if (lmax < lmin * 1.0001f) lmax = lmin * 1.0001f;
        const float theta = 0.5f * (lmax + lmin);
        const float delta = 0.5f * (lmax - lmin);
        scalars[0] = theta;
        scalars[1] = delta;
        scalars[2] = theta / delta;  // sigma1
        scalars[3] = lmin;
    }
}

// async global(16B) -> LDS. aux=0: normal (L2-cached). aux=17 (SC0|SC1):
// system-scope, bypasses L2 (reads L3 coherency point) -- used for d, which
// is only ever accessed with sc0sc1 ops so no stale L2 copy can exist.
#define GLOAD16(g, l)                                                        \
    __builtin_amdgcn_global_load_lds(                                        \
        (const __attribute__((address_space(1))) void*)(g),                  \
        (__attribute__((address_space(3))) void*)(l), 16, 0, 0)
#define GLOAD16_SC(g, l)                                                     \
    __builtin_amdgcn_global_load_lds(                                        \
        (const __attribute__((address_space(1))) void*)(g),                  \
        (__attribute__((address_space(3))) void*)(l), 16, 0, 17)

__device__ __forceinline__ void stage16k(const float* __restrict__ g, float* l, int t) {
    #pragma unroll
    for (int u = 0; u < 4; ++u) {
        const int o = (u * 256 + t) * 4;
        GLOAD16(g + o, l + o);
    }
}

__device__ __forceinline__ void stage16k_sc(const float* __restrict__ g, float* l, int t) {
    #pragma unroll
    for (int u = 0; u < 4; ++u) {
        const int o = (u * 256 + t) * 4;
        GLOAD16_SC(g + o, l + o);
    }
}

// Lightweight device-wide barrier, slot k. Entry drains this block's
// system-scope d stores (vmcnt0); 2-level counter tree -> flag; spin on
// system-scope flag loads. No cache maintenance needed: d is always
// accessed sc0sc1 (L2-bypassing), counters/flag are atomics.
__device__ __forceinline__ void gbarrier(int* cnt, int* flg, int k, int bid) {
    asm volatile("s_waitcnt vmcnt(0)" ::: "memory");
    __syncthreads();
    if (threadIdx.x == 0) {
        int* c = cnt + k * 544;
        bool last = false;
        if (atomicAdd(&c[(bid & 15) * 32], 1) == 15) {
            if (atomicAdd(&c[512], 1) == 15) {
                __hip_atomic_store(&flg[k], 1, __ATOMIC_RELAXED, __HIP_MEMORY_SCOPE_SYSTEM);
                last = true;
            }
        }
        if (!last) {
            while (__hip_atomic_load(&flg[k], __ATOMIC_RELAXED, __HIP_MEMORY_SCOPE_SYSTEM) == 0) {
                __builtin_amdgcn_s_sleep(1);
            }
        }
    }
    __syncthreads();
}

// Fused: init + K_CHEB Chebyshev iterations + final x+=d + leaky-relu.
// Block b owns rows [4b, 4b+4). x,r,d slice in registers; op rows in LDS.
// d chunks: 4-buffer, depth-3 prefetch, counted vmcnt (12/8/4/0 ledger).
__global__ __launch_bounds__(256)
void cheb_fused(const float* __restrict__ op, const float* __restrict__ scalars,
                const float* __restrict__ fts, const float* __restrict__ dtime,
                float* __restrict__ d0, float* __restrict__ d1,
                int* __restrict__ cnt, int* __restrict__ flg,
                float* __restrict__ out) {
    __shared__ float op_s[4 * NN];        // 16 KB, persistent all iterations
    __shared__ float dbuf[4][4096];       // 4 x 16 KB chunk buffers
    __shared__ float red_s[4][16][16];    // 4 KB cross-wave reduction

    const int t = threadIdx.x;
    const int b = blockIdx.x;
    const int i0 = b * 4;

    const int rr_u = t >> 6;
    const int w_u  = t & 63;
    const int c0 = (t & 15) * 4;
    const int jg = t >> 4;

    // stage op rows (16 KB contiguous) once
    stage16k(op + i0 * NN, op_s, t);

    const float theta  = scalars[0];
    const float delta  = scalars[1];
    const float sigma1 = scalars[2];

    // init own elements; d0 published system-scope (visible at L3)
    const float dtw  = fmaxf(dtime[w_u], 1e-8f);
    const float bval = fts[i0 * WW + t] / dtw;
    float x_e = 0.f, r_e = bval, d_e = bval / theta;
    __hip_atomic_store(&d0[i0 * WW + t], d_e, __ATOMIC_RELAXED, __HIP_MEMORY_SCOPE_SYSTEM);

    asm volatile("s_waitcnt vmcnt(0)" ::: "memory");
    __builtin_amdgcn_sched_barrier(0);
    __syncthreads();     // op_s ready for all waves
    gbarrier(cnt, flg, 0, b);   // d0 globally visible

    float rho = 1.0f / sigma1;

    for (int k = 0; k < K_CHEB; ++k) {
        const float* din = (k & 1) ? d1 : d0;
        float*      dout = (k & 1) ? d0 : d1;

        float4 a0 = {0.f,0.f,0.f,0.f}, a1 = a0, a2 = a0, a3 = a0;

        // prologue: 3 chunks in flight (12 outstanding loads/thread)
        stage16k_sc(din,        dbuf[0], t);
        stage16k_sc(din + 4096, dbuf[1], t);
        stage16k_sc(din + 8192, dbuf[2], t);
        for (int c = 0; c < 16; ++c) {
            if (c < 13) {
                stage16k_sc(din + (c + 3) * 4096, dbuf[(c + 3) & 3], t);
                asm volatile("s_waitcnt vmcnt(12)" ::: "memory");  // chunk c landed
            } else if (c == 13) {
                asm volatile("s_waitcnt vmcnt(8)" ::: "memory");
            } else if (c == 14) {
                asm volatile("s_waitcnt vmcnt(4)" ::: "memory");
            } else {
                asm volatile("s_waitcnt vmcnt(0)" ::: "memory");
            }
            __builtin_amdgcn_sched_barrier(0);
            __builtin_amdgcn_s_barrier();                // chunk c ready

            const float* db = dbuf[c & 3];
            const int jb = jg * 4;
            float4 o0 = *(const float4*)&op_s[0 * NN + c * 64 + jb];
            float4 o1 = *(const float4*)&op_s[1 * NN + c * 64 + jb];
            float4 o2 = *(const float4*)&op_s[2 * NN + c * 64 + jb];
            float4 o3 = *(const float4*)&op_s[3 * NN + c * 64 + jb];
            #pragma unroll
            for (int jj = 0; jj < 4; ++jj) {
                float4 dv = *(const float4*)&db[(jb + jj) * 64 + c0];
                const float f0 = ((const float*)&o0)[jj];
                const float f1 = ((const float*)&o1)[jj];
                const float f2 = ((const float*)&o2)[jj];
                const float f3 = ((const float*)&o3)[jj];
                a0.x += f0 * dv.x; a0.y += f0 * dv.y; a0.z += f0 * dv.z; a0.w += f0 * dv.w;
                a1.x += f1 * dv.x; a1.y += f1 * dv.y; a1.z += f1 * dv.z; a1.w += f1 * dv.w;
                a2.x += f2 * dv.x; a2.y += f2 * dv.y; a2.z += f2 * dv.z; a2.w += f2 * dv.w;
                a3.x += f3 * dv.x; a3.y += f3 * dv.y; a3.z += f3 * dv.z; a3.w += f3 * dv.w;
            }
            asm volatile("s_waitcnt lgkmcnt(0)" ::: "memory");
            __builtin_amdgcn_sched_barrier(0);
            __builtin_amdgcn_s_barrier();                // all done reading dbuf[c&3]
        }

        // reduce over the 16 jg groups. a[v], v = row*4 + col-sub
        float a[16] = {a0.x, a0.y, a0.z, a0.w, a1.x, a1.y, a1.z, a1.w,
                       a2.x, a2.y, a2.z, a2.w, a3.x, a3.y, a3.z, a3.w};
        #pragma unroll
        for (int v = 0; v < 16; ++v) {
            a[v] += __shfl_xor(a[v], 16, 64);
            a[v] += __shfl_xor(a[v], 32, 64);
        }
        const int wv = t >> 6, lane = t & 63;
        if (lane < 16) {
            #pragma unroll
            for (int v = 0; v < 16; ++v) red_s[wv][lane][v] = a[v];
        }
        __syncthreads();
        const int ri = w_u >> 2;
        const int vi = rr_u * 4 + (w_u & 3);
        const float q = red_s[0][ri][vi] + red_s[1][ri][vi] +
                        red_s[2][ri][vi] + red_s[3][ri][vi];

        // Chebyshev update (row-local, registers)
        x_e += d_e;
        r_e -= q;
        const float rho_n = 1.0f / (2.f * sigma1 - rho);
        d_e = rho_n * rho * d_e + (2.f * rho_n / delta) * r_e;
        rho = rho_n;
        __hip_atomic_store(&dout[i0 * WW + t], d_e, __ATOMIC_RELAXED, __HIP_MEMORY_SCOPE_SYSTEM);

        gbarrier(cnt, flg, k + 1, b);   // dout visible to all before next matvec
    }

    // closing half-step + leaky relu
    x_e += d_e;
    out[i0 * WW + t] = x_e > 0.f ? x_e : 0.01f * x_e;
}

extern "C" void kernel_launch(void* const* d_in, const int* in_sizes, int n_in,
                              void* d_out, int out_size, void* d_ws, size_t ws_size,
                              hipStream_t stream) {
    const float* node_fts = (const float*)d_in[0];
    const float* m_adv    = (const float*)d_in[3];
    const float* m_diff   = (const float*)d_in[4];
    const float* dtime    = (const float*)d_in[7];
    const float* ga       = (const float*)d_in[8];
    const float* gd       = (const float*)d_in[9];
    const float* al       = (const float*)d_in[10];
    float* out = (float*)d_out;

    float* ws      = (float*)d_ws;
    float* op      = ws + OFF_OP;
    float* rowsum  = ws + OFF_RS;
    float* scalars = ws + OFF_SC;
    int*   cnt     = (int*)(ws + OFF_CNT);
    int*   flg     = (int*)(ws + OFF_FLG);
    float* dbuf0   = ws + OFF_D0;
    float* dbuf1   = ws + OFF_D1;

    zero_aux<<<105, 256, 0, stream>>>(rowsum, cnt, flg);
    form_op<<<dim3(16, 16), 256, 0, stream>>>(m_adv, m_diff, ga, gd, al, op, rowsum);
    reduce_scalars<<<1, 256, 0, stream>>>(rowsum, ga, gd, al, scalars);

    const float* c_op = op; const float* c_sc = scalars;
    void* args[] = {(void*)&c_op, (void*)&c_sc, (void*)&node_fts, (void*)&dtime,
                    (void*)&dbuf0, (void*)&dbuf1, (void*)&cnt, (void*)&flg,
                    (void*)&out};
    hipLaunchCooperativeKernel(reinterpret_cast<void*>(cheb_fused),
                               dim3(NBLK), dim3(256), args, 0, stream);
}